// Round 2
// baseline (10995.901 us; speedup 1.0000x reference)
//
#include <hip/hip_runtime.h>
#include <hip/hip_bf16.h>

typedef __hip_bfloat16 bf16;

#define SEQ   256
#define BATCH 64
#define EMBED 512
#define HIDDEN 512
#define VOCAB 10000
#define GDIM  2048              // 4*HIDDEN
#define SB    16384             // SEQ*BATCH
#define BH    32768             // BATCH*HIDDEN

// ---------------- pack kernel: wx*/wh* -> [512][2048] fp32, biases -> fp32[2048]
__global__ void pack_weights(const float* __restrict__ wxi, const float* __restrict__ wxf,
                             const float* __restrict__ wxc, const float* __restrict__ wxo,
                             const float* __restrict__ whi, const float* __restrict__ whf,
                             const float* __restrict__ whc, const float* __restrict__ who,
                             const float* __restrict__ bi,  const float* __restrict__ bfp,
                             const float* __restrict__ bc,  const float* __restrict__ bo,
                             float* __restrict__ wxp, float* __restrict__ whp,
                             float* __restrict__ bg) {
    int i = blockIdx.x * 256 + threadIdx.x;
    if (i < 512 * GDIM) {
        int k = i >> 11, colg = i & (GDIM - 1);
        int g = colg >> 9, j = colg & 511;
        const float* wx = (g == 0) ? wxi : (g == 1) ? wxf : (g == 2) ? wxc : wxo;
        const float* wh = (g == 0) ? whi : (g == 1) ? whf : (g == 2) ? whc : who;
        wxp[i] = wx[k * 512 + j];
        whp[i] = wh[k * 512 + j];
        if (i < GDIM) {
            const float* bb = (g == 0) ? bi : (g == 1) ? bfp : (g == 2) ? bc : bo;
            bg[i] = bb[j];
        }
    }
}

// ---------------- generic tiled GEMM: C[M,N] = A[M,K] * B[K,N] + bias
// A: fp32 (optionally gathered rows via idx); B: fp32; C: fp32.
template <bool GATHER>
__global__ void gemm_k(const float* __restrict__ A, const int* __restrict__ idx,
                       const float* __restrict__ B,
                       const float* __restrict__ bias,
                       float* __restrict__ C, int M, int N, int K) {
    __shared__ float As[16][65];
    __shared__ float Bs[16][65];
    const int tid = threadIdx.x;
    const int tr = tid >> 4, tc = tid & 15;
    const int rowBase = blockIdx.y * 64, colBase = blockIdx.x * 64;

    // Per-thread A-row pointers (fixed across K loop)
    const float* arow[4];
#pragma unroll
    for (int p = 0; p < 4; ++p) {
        int lin = tid + p * 256;
        int r = lin >> 4;
        int grow = rowBase + r;
        if (GATHER) arow[p] = A + (size_t)idx[grow] * K;
        else        arow[p] = A + (size_t)grow * K;
    }

    float acc[4][4] = {};
    for (int k0 = 0; k0 < K; k0 += 16) {
#pragma unroll
        for (int p = 0; p < 4; ++p) {
            int lin = tid + p * 256;
            int kk = lin & 15, r = lin >> 4;
            As[kk][r] = arow[p][k0 + kk];
        }
#pragma unroll
        for (int p = 0; p < 4; ++p) {
            int lin = tid + p * 256;
            int n = lin & 63, kk = lin >> 6;
            int col = colBase + n;
            Bs[kk][n] = (col < N) ? B[(size_t)(k0 + kk) * N + col] : 0.f;
        }
        __syncthreads();
#pragma unroll
        for (int kk = 0; kk < 16; ++kk) {
            float a[4], b[4];
#pragma unroll
            for (int i = 0; i < 4; ++i) a[i] = As[kk][tr * 4 + i];
#pragma unroll
            for (int j = 0; j < 4; ++j) b[j] = Bs[kk][tc * 4 + j];
#pragma unroll
            for (int i = 0; i < 4; ++i)
#pragma unroll
                for (int j = 0; j < 4; ++j)
                    acc[i][j] += a[i] * b[j];
        }
        __syncthreads();
    }

#pragma unroll
    for (int i = 0; i < 4; ++i) {
        int row = rowBase + tr * 4 + i;
#pragma unroll
        for (int j = 0; j < 4; ++j) {
            int col = colBase + tc * 4 + j;
            if (col < N) {
                float v = acc[i][j];
                if (bias) v += bias[col];
                C[(size_t)row * N + col] = v;
            }
        }
    }
}

// ---------------- one LSTM timestep
// grid (16 jblk, 16 bblk), block 256. Each thread: one (gate, j) column, 2 batch rows.
__global__ void lstm_step(const float* __restrict__ xp,    // [64, 2048] for this t
                          const float* __restrict__ whp,   // [512][2048]
                          const float* __restrict__ h_prev,// [64,512]
                          float* __restrict__ h_out,       // [64,512]
                          float* __restrict__ c) {         // [64,512] in/out
    __shared__ float hsm[4][512];
    __shared__ float gs[4][4][32];  // [gate][b_local][j]
    const int tid = threadIdx.x;
    const int j0 = blockIdx.x * 32;
    const int b0 = blockIdx.y * 4;

#pragma unroll
    for (int p = 0; p < 8; ++p) {
        int lin = tid + p * 256;
        int bl = lin >> 9, kk = lin & 511;
        hsm[bl][kk] = h_prev[(size_t)(b0 + bl) * 512 + kk];
    }
    __syncthreads();

    const int jj = tid & 31;
    const int gate = (tid >> 5) & 3;
    const int bt = tid >> 7;             // 0 or 1, uniform per wave
    const int col = gate * 512 + j0 + jj;
    const int bl0 = bt * 2, bl1 = bt * 2 + 1;

    float acc0 = xp[(size_t)(b0 + bl0) * GDIM + col];
    float acc1 = xp[(size_t)(b0 + bl1) * GDIM + col];
#pragma unroll 4
    for (int k = 0; k < 512; ++k) {
        float w = whp[(size_t)k * GDIM + col];
        acc0 += w * hsm[bl0][k];
        acc1 += w * hsm[bl1][k];
    }
    gs[gate][bl0][jj] = acc0;
    gs[gate][bl1][jj] = acc1;
    __syncthreads();

    if (tid < 128) {
        int bl = tid >> 5;
        int j = tid & 31;
        float gi = gs[0][bl][j], gf = gs[1][bl][j], gc = gs[2][bl][j], go = gs[3][bl][j];
        float it = 1.f / (1.f + __expf(-gi));
        float ft = 1.f / (1.f + __expf(-gf));
        float cc = tanhf(gc);
        float ot = 1.f / (1.f + __expf(-go));
        size_t off = (size_t)(b0 + bl) * 512 + j0 + j;
        float cn = ft * c[off] + it * cc;
        c[off] = cn;
        h_out[off] = ot * tanhf(cn);
    }
}

// ---------------- write ht, ct (fp32) to output tail
__global__ void finalize(const float* __restrict__ hlast, const float* __restrict__ c,
                         float* __restrict__ out) {
    int i = blockIdx.x * 256 + threadIdx.x;  // 65536 threads
    if (i < BH) out[(size_t)SB * VOCAB + i] = hlast[i];
    else        out[(size_t)SB * VOCAB + i] = c[i - BH];
}

extern "C" void kernel_launch(void* const* d_in, const int* in_sizes, int n_in,
                              void* d_out, int out_size, void* d_ws, size_t ws_size,
                              hipStream_t stream) {
    const int*   input_ = (const int*)d_in[0];
    const float* emb = (const float*)d_in[1];
    const float* wxi = (const float*)d_in[2];
    const float* whi = (const float*)d_in[3];
    const float* bi  = (const float*)d_in[4];
    const float* wxf = (const float*)d_in[5];
    const float* whf = (const float*)d_in[6];
    const float* bfp = (const float*)d_in[7];
    const float* wxc = (const float*)d_in[8];
    const float* whc = (const float*)d_in[9];
    const float* bc  = (const float*)d_in[10];
    const float* wxo = (const float*)d_in[11];
    const float* who = (const float*)d_in[12];
    const float* bo  = (const float*)d_in[13];
    const float* wy  = (const float*)d_in[14];
    const float* by  = (const float*)d_in[15];
    float* out = (float*)d_out;

    // Workspace carve-up: hs (33.55 MB) + h0/c (0.26 MB) + whp/wxp fp32 (16 MB) + bg
    char* ws = (char*)d_ws;
    float* hs  = (float*)ws;                                   // SEQ*BH fp32
    float* h0  = (float*)(ws + (size_t)SEQ * BH * 4);          // BH fp32
    float* c   = (float*)(ws + (size_t)SEQ * BH * 4 + BH * 4); // BH fp32
    float* whp = (float*)(ws + (size_t)SEQ * BH * 4 + 2 * BH * 4);
    float* wxp = whp + (size_t)512 * GDIM;
    float* bg  = wxp + (size_t)512 * GDIM;

    // xp [SB, GDIM] fp32 (134 MB) lives in d_out's byte range (655 MB fp32);
    // consumed by the scan before the logits GEMM overwrites it.
    float* xp = (float*)d_out;

    // 1) zero h0 and c (contiguous)
    hipMemsetAsync(h0, 0, 2 * (size_t)BH * 4, stream);

    // 2) pack weights
    pack_weights<<<(512 * GDIM + 255) / 256, 256, 0, stream>>>(
        wxi, wxf, wxc, wxo, whi, whf, whc, who, bi, bfp, bc, bo, wxp, whp, bg);

    // 3) x-proj GEMM with fused embedding gather: xp = emb[input_] @ Wx + b
    gemm_k<true><<<dim3(GDIM / 64, SB / 64), 256, 0, stream>>>(
        emb, input_, wxp, bg, xp, SB, GDIM, EMBED);

    // 4) recurrent scan
    for (int t = 0; t < SEQ; ++t) {
        const float* hprev = (t == 0) ? h0 : hs + (size_t)(t - 1) * BH;
        lstm_step<<<dim3(16, 16), 256, 0, stream>>>(
            xp + (size_t)t * BATCH * GDIM, whp, hprev, hs + (size_t)t * BH, c);
    }

    // 5) ht / ct outputs
    finalize<<<(2 * BH) / 256, 256, 0, stream>>>(hs + (size_t)(SEQ - 1) * BH, c, out);

    // 6) logits GEMM: out[0 : SB*VOCAB] = hs @ wy + by (fp32)
    gemm_k<false><<<dim3((VOCAB + 63) / 64, SB / 64), 256, 0, stream>>>(
        hs, nullptr, wy, by, out, SB, VOCAB, EMBED);
}